// Round 8
// baseline (605.499 us; speedup 1.0000x reference)
//
#include <hip/hip_runtime.h>

#define S_DIM 512
#define H_DIM 512
#define NH 256
#define SROW 520   // 512 + 8-half pad per row (per-row DMA base keeps this legal)

#define AS1 __attribute__((address_space(1)))
#define AS3 __attribute__((address_space(3)))

typedef _Float16 half8 __attribute__((ext_vector_type(8)));
typedef float f32x16 __attribute__((ext_vector_type(16)));

// ---- k0: prep GEMM (blocks 0..255) + W2 fragment-major convert (blocks 256..319) --
// prep: [1024x512]@[512x1024] fp32-in (inline f16 cvt), f16 out. Block 256 = 4 waves
// (2mg x 2ng), block tile 64M x 64N, wave 32x32, K fully unrolled.
__global__ __launch_bounds__(256) void prep_kernel(const float* __restrict__ feats,
        const float* __restrict__ W1, const float* __restrict__ b1,
        const float* __restrict__ W2,
        _Float16* __restrict__ aH, _Float16* __restrict__ cH, _Float16* __restrict__ w2L) {
    const int blk = blockIdx.x;
    const int tid = threadIdx.x;
    if (blk >= 256) {   // W2 [512,256] -> fragment-major f16: chunk (gcb,n) at (gcb*256+n)*8
        int t = (blk - 256) * 256 + tid;   // 16384
        int gcb = t >> 8, n = t & 255;
        half8 v;
#pragma unroll
        for (int j = 0; j < 8; j++) v[j] = (_Float16)W2[(size_t)(gcb * 8 + j) * NH + n];
        *(half8*)&w2L[((size_t)gcb * 256 + n) * 8] = v;
        return;
    }
    const int wave = tid >> 6, lane = tid & 63;
    const int m32 = lane & 31, ch = lane >> 5;
    const int mg = wave >> 1, ng = wave & 1;
    const int m0 = (blk >> 4) * 64 + mg * 32;
    const int n = (blk & 15) * 64 + ng * 32 + m32;            // 0..1023
    const bool fh = (n < H_DIM);
    const float* wcol = fh ? &W1[n] : &W1[(size_t)H_DIM * H_DIM + (n - H_DIM)];
    const float* arow = &feats[(size_t)(m0 + m32) * H_DIM + ch * 8];

    f32x16 acc = (f32x16)0.f;
#pragma unroll
    for (int ks = 0; ks < 32; ks++) {
        const int kbase = ks * 16 + ch * 8;
        float4 a0 = *(const float4*)&arow[ks * 16];
        float4 a1 = *(const float4*)&arow[ks * 16 + 4];
        half8 af, bf;
        af[0] = (_Float16)a0.x; af[1] = (_Float16)a0.y;
        af[2] = (_Float16)a0.z; af[3] = (_Float16)a0.w;
        af[4] = (_Float16)a1.x; af[5] = (_Float16)a1.y;
        af[6] = (_Float16)a1.z; af[7] = (_Float16)a1.w;
#pragma unroll
        for (int j = 0; j < 8; j++) bf[j] = (_Float16)wcol[(size_t)(kbase + j) * H_DIM];
        acc = __builtin_amdgcn_mfma_f32_32x32x16_f16(af, bf, acc, 0, 0, 0);
    }
    const float bias = fh ? b1[n] : 0.f;
#pragma unroll
    for (int r = 0; r < 16; r++) {
        int m = m0 + (r & 3) + 8 * (r >> 2) + 4 * ch;
        float v = acc[r] + bias;
        if (fh) aH[(size_t)m * H_DIM + n] = (_Float16)v;
        else    cH[(size_t)m * H_DIM + (n - H_DIM)] = (_Float16)v;
    }
}

// ---- k1: persistent pair GEMM. grid 512 x 512 thr (2 blocks/CU). -------------------
// Block p: b = p>>8, it = (p>>3)&31, jt = (p&7)*8 + s for s in 0..7.
// sa (16 i-rows) staged once; sc (8 j-rows) double-buffered, prefetched per tile.
// 8 waves = 2 mg x 4 ng; wave = 64 pairs x 64 N; 32x32x16 MFMA, B from global (L2).
__global__ __launch_bounds__(512, 4) void pair_kernel(
        const _Float16* __restrict__ aH, const _Float16* __restrict__ cH,
        const _Float16* __restrict__ w2L,
        const float* __restrict__ b2, const float* __restrict__ W3,
        const float* __restrict__ b3, float* __restrict__ out) {
    const int p = blockIdx.x;
    const int g = p >> 3, q = p & 7;
    const int b = g >> 5, it = g & 31;
    const int i0 = it * 16;
    const int jbase = q * 64;                 // j0(s) = jbase + s*8

    __shared__ __align__(16) _Float16 sa[16 * SROW];      // 16.25 KB
    __shared__ __align__(16) _Float16 sc2[2][8 * SROW];   // 16.25 KB
    __shared__ float spart[2 * 64 * 32];                  // 16 KB

    const int tid = threadIdx.x;
    const int wave = tid >> 6, lane = tid & 63;
    const int mg = wave >> 2, ng = wave & 3;
    const int nb = ng * 64;
    const int m32 = lane & 31, ch = lane >> 5;

    // ---- initial staging: each wave DMAs a-rows {wave, wave+8} and c-row {wave} ----
    __builtin_amdgcn_global_load_lds(
        (const AS1 unsigned int*)&aH[((size_t)(b * S_DIM + i0 + wave)) * H_DIM + lane * 8],
        (AS3 unsigned int*)&sa[wave * SROW], 16, 0, 0);
    __builtin_amdgcn_global_load_lds(
        (const AS1 unsigned int*)&aH[((size_t)(b * S_DIM + i0 + wave + 8)) * H_DIM + lane * 8],
        (AS3 unsigned int*)&sa[(wave + 8) * SROW], 16, 0, 0);
    __builtin_amdgcn_global_load_lds(
        (const AS1 unsigned int*)&cH[((size_t)(b * S_DIM + jbase + wave)) * H_DIM + lane * 8],
        (AS3 unsigned int*)&sc2[0][wave * SROW], 16, 0, 0);

    const int il0 = mg * 8 + (m32 >> 3);      // mt=0 a-row
    const int il1 = il0 + 4;                  // mt=1 a-row
    const int jl = m32 & 7;
    const _Float16* vaB0 = &sa[il0 * SROW + ch * 8];
    const _Float16* vaB1 = &sa[il1 * SROW + ch * 8];

    // tile-invariant epilogue coefficients
    float b2v[2], w3v[2];
#pragma unroll
    for (int nt = 0; nt < 2; nt++) {
        int n = nb + nt * 32 + m32;
        b2v[nt] = b2[n];
        w3v[nt] = W3[n];
    }
    const float b3v = b3[0];

    __syncthreads();   // initial sa/sc staged

#pragma unroll 1
    for (int s = 0; s < 8; s++) {
        const int cur = s & 1;
        if (s < 7) {   // prefetch next tile's c-rows into the other buffer (hidden)
            __builtin_amdgcn_global_load_lds(
                (const AS1 unsigned int*)
                    &cH[((size_t)(b * S_DIM + jbase + (s + 1) * 8 + wave & 0x7fffffff)) * H_DIM + lane * 8],
                (AS3 unsigned int*)&sc2[cur ^ 1][wave * SROW], 16, 0, 0);
        }
        const _Float16* vcB = &sc2[cur][jl * SROW + ch * 8];

        f32x16 acc[2][2];
#pragma unroll
        for (int mt = 0; mt < 2; mt++)
#pragma unroll
            for (int nt = 0; nt < 2; nt++) acc[mt][nt] = (f32x16)0.f;

        // B fragment-major: chunk (kc,n) at (kc*256+n)*8 halves; kc = ks*2 + ch
        const _Float16* bp = &w2L[((size_t)ch * 256 + nb + m32) * 8];
        half8 bB[2][2];
        bB[0][0] = *(const half8*)&bp[0];
        bB[0][1] = *(const half8*)&bp[256];
        bB[1][0] = *(const half8*)&bp[4096];
        bB[1][1] = *(const half8*)&bp[4096 + 256];

#pragma unroll
        for (int ks = 0; ks < 32; ks++) {
            const int curk = ks & 1;
            half8 bf0 = bB[curk][0], bf1 = bB[curk][1];
            if (ks < 30) {
                const _Float16* bn = bp + (size_t)(ks + 2) * 4096;
                bB[curk][0] = *(const half8*)&bn[0];
                bB[curk][1] = *(const half8*)&bn[256];
            }
            half8 vc  = *(const half8*)&vcB[ks * 16];
            half8 va0 = *(const half8*)&vaB0[ks * 16];
            half8 va1 = *(const half8*)&vaB1[ks * 16];
            half8 af0 = __builtin_elementwise_max(va0 + vc, (half8)(_Float16)0.f);
            half8 af1 = __builtin_elementwise_max(va1 + vc, (half8)(_Float16)0.f);
            acc[0][0] = __builtin_amdgcn_mfma_f32_32x32x16_f16(af0, bf0, acc[0][0], 0, 0, 0);
            acc[0][1] = __builtin_amdgcn_mfma_f32_32x32x16_f16(af0, bf1, acc[0][1], 0, 0, 0);
            acc[1][0] = __builtin_amdgcn_mfma_f32_32x32x16_f16(af1, bf0, acc[1][0], 0, 0, 0);
            acc[1][1] = __builtin_amdgcn_mfma_f32_32x32x16_f16(af1, bf1, acc[1][1], 0, 0, 0);
        }

        __syncthreads();   // all waves past K-loop (prev gather done; DMA drained)

        // ---- epilogue: relu(acc+b2).W3, pre-reduce, scatter to spart ----
#pragma unroll
        for (int mt = 0; mt < 2; mt++)
#pragma unroll
            for (int r = 0; r < 16; r++) {
                float sv = 0.f;
#pragma unroll
                for (int nt = 0; nt < 2; nt++) {
                    float v = acc[mt][nt][r] + b2v[nt];
                    v = v > 0.f ? v : 0.f;
                    sv += v * w3v[nt];
                }
                sv += __shfl_xor(sv, 8);
                sv += __shfl_xor(sv, 16);
                if (m32 < 8) {
                    int row = mt * 32 + (r & 3) + 8 * (r >> 2) + 4 * ch;
                    int col = ng * 8 + m32;
                    spart[mg * 2048 + row * 32 + ((col + row) & 31)] = sv;
                }
            }
        __syncthreads();   // spart ready

        // ---- gather 32 col-groups, sigmoid, store ----
        {
            const int R = tid >> 2, sub = tid & 3;   // R = block pair row 0..127
            const int mgf = R >> 6, rowf = R & 63;
            const float* base = &spart[mgf * 2048 + rowf * 32];
            float sv = 0.f;
#pragma unroll
            for (int k = 0; k < 8; k++) sv += base[(sub * 8 + k + rowf) & 31];
            sv += __shfl_xor(sv, 1);
            sv += __shfl_xor(sv, 2);
            if (sub == 0) {
                float tot = sv + b3v;
                float sg = 1.f / (1.f + __expf(-tot));
                int i = i0 + (R >> 3), j = jbase + s * 8 + (R & 7);
                out[(size_t)b * S_DIM * S_DIM + (size_t)i * S_DIM + j] = sg;
            }
        }
    }
}

extern "C" void kernel_launch(void* const* d_in, const int* in_sizes, int n_in,
                              void* d_out, int out_size, void* d_ws, size_t ws_size,
                              hipStream_t stream) {
    const float* feats = (const float*)d_in[0];
    const float* W1 = (const float*)d_in[1];
    const float* b1 = (const float*)d_in[2];
    const float* W2 = (const float*)d_in[3];
    const float* b2 = (const float*)d_in[4];
    const float* W3 = (const float*)d_in[5];
    const float* b3 = (const float*)d_in[6];
    float* out = (float*)d_out;

    char* ws = (char*)d_ws;
    _Float16* aH   = (_Float16*)ws;                 // [1024][512] f16 = 1 MB
    _Float16* cH   = (_Float16*)(ws + (1 << 20));   // [1024][512] f16 = 1 MB
    _Float16* w2L  = (_Float16*)(ws + (2 << 20));   // 256 KB fragment-major

    prep_kernel<<<320, 256, 0, stream>>>(feats, W1, b1, W2, aH, cH, w2L);
    pair_kernel<<<512, 512, 0, stream>>>(aH, cH, w2L, b2, W3, b3, out);
}